// Round 4
// baseline (107.442 us; speedup 1.0000x reference)
//
#include <hip/hip_runtime.h>

#define NN 10000
#define NE 80000
#define NB 2
#define NT 12
#define NF 64
#define ROWS (NB*NN*NT)        // 240000

typedef __attribute__((ext_vector_type(8))) short bf16x8;
typedef __attribute__((ext_vector_type(4))) float f32x4;

__device__ __forceinline__ unsigned short f2b(float f) {   // f32 -> bf16 RNE
    unsigned int u = __builtin_bit_cast(unsigned int, f);
    u += 0x7fffu + ((u >> 16) & 1u);
    return (unsigned short)(u >> 16);
}
__device__ __forceinline__ float b2f_lo(unsigned int u){ return __builtin_bit_cast(float, u << 16); }
__device__ __forceinline__ float b2f_hi(unsigned int u){ return __builtin_bit_cast(float, u & 0xffff0000u); }

// ---------------- K0: weights -> bf16 (+ column permutation for W_neigh) ----------
__global__ __launch_bounds__(256) void k_prep(const float* __restrict__ Wp,
        const float* __restrict__ Wn, const float* __restrict__ Ws,
        unsigned short* __restrict__ Wp_b, unsigned short* __restrict__ Wcat) {
    int t = threadIdx.x;
    for (int i = t; i < 4096; i += 256) {
        Wp_b[i] = f2b(Wp[i]);
        int o = i >> 6, g = i & 63;
        Wcat[o*128 + g] = f2b(Ws[i]);
        Wcat[o*128 + 64 + ((g & 15)*4 + (g >> 4))] = f2b(Wn[i]);
    }
}

// ---------------- K1: msg = relu(x @ Wp^T + bp) via MFMA; emits xb=bf16(x) --------
// msg stored NODE-MAJOR: msg[((node*24) + b*12 + t)*64 + perm_col], so one edge's
// gather is a single contiguous 3KB block. xb stays b-major.
__global__ __launch_bounds__(256) void k_msg(const float* __restrict__ x,
        const unsigned short* __restrict__ Wp_b, const float* __restrict__ bp,
        unsigned short* __restrict__ msg, unsigned short* __restrict__ xb) {
    __shared__ __align__(16) unsigned short A[128*72];   // [row][K=64 pad 72]
    __shared__ __align__(16) unsigned short W[64*72];
    int tid = threadIdx.x;
    {   // stage weights: 64*64 shorts
        int row = tid >> 2, c = (tid & 3) * 16;
        bf16x8 w0 = *(const bf16x8*)(Wp_b + row*64 + c);
        bf16x8 w1 = *(const bf16x8*)(Wp_b + row*64 + c + 8);
        *(bf16x8*)(W + row*72 + c)     = w0;
        *(bf16x8*)(W + row*72 + c + 8) = w1;
    }
    int m0 = blockIdx.x * 128;
    #pragma unroll
    for (int k = 0; k < 8; ++k) {
        int c = tid + 256*k;                   // 0..2047 float4-chunks
        int row = c >> 4, f0 = (c & 15) * 4;
        float4 v = *(const float4*)(x + (size_t)(m0 + row)*64 + f0);
        uint2 p;
        p.x = f2b(v.x) | ((unsigned int)f2b(v.y) << 16);
        p.y = f2b(v.z) | ((unsigned int)f2b(v.w) << 16);
        *(uint2*)(A + row*72 + f0) = p;
        *(uint2*)(xb + (size_t)(m0 + row)*64 + f0) = p;
    }
    __syncthreads();

    int lane = tid & 63, w = tid >> 6;
    int cl = lane & 15, gq = lane >> 4;
    f32x4 acc[2][4] = {};
    #pragma unroll
    for (int kk = 0; kk < 2; ++kk) {
        int ko = kk*32 + gq*8;
        bf16x8 a0 = *(const bf16x8*)(A + (w*32 + cl)*72 + ko);
        bf16x8 a1 = *(const bf16x8*)(A + (w*32 + 16 + cl)*72 + ko);
        #pragma unroll
        for (int nf = 0; nf < 4; ++nf) {
            bf16x8 b = *(const bf16x8*)(W + (nf*16 + cl)*72 + ko);
            acc[0][nf] = __builtin_amdgcn_mfma_f32_16x16x32_bf16(a0, b, acc[0][nf], 0,0,0);
            acc[1][nf] = __builtin_amdgcn_mfma_f32_16x16x32_bf16(a1, b, acc[1][nf], 0,0,0);
        }
    }
    float bpv[4];
    #pragma unroll
    for (int nf = 0; nf < 4; ++nf) bpv[nf] = bp[nf*16 + cl];
    #pragma unroll
    for (int m = 0; m < 2; ++m)
    #pragma unroll
    for (int r = 0; r < 4; ++r) {
        int row = m0 + w*32 + m*16 + gq*4 + r;   // global b-major row
        int b  = row / (NN*NT);
        int rem = row - b*(NN*NT);
        int node = rem / NT, t = rem - node*NT;
        float v0 = fmaxf(acc[m][0][r] + bpv[0], 0.f);
        float v1 = fmaxf(acc[m][1][r] + bpv[1], 0.f);
        float v2 = fmaxf(acc[m][2][r] + bpv[2], 0.f);
        float v3 = fmaxf(acc[m][3][r] + bpv[3], 0.f);
        uint2 p;
        p.x = f2b(v0) | ((unsigned int)f2b(v1) << 16);
        p.y = f2b(v2) | ((unsigned int)f2b(v3) << 16);
        *(uint2*)(msg + ((size_t)(node*24 + b*12 + t)*64) + cl*4) = p;
    }
}

// ---------------- K2: CSR build (count -> scan -> scatter) ----------------
__global__ void k_count(const int* __restrict__ dst, int* __restrict__ cnt) {
    int e = blockIdx.x * blockDim.x + threadIdx.x;
    if (e < NE) atomicAdd(&cnt[dst[e]], 1);
}

__global__ __launch_bounds__(1024) void k_scan(const int* __restrict__ cnt,
        int* __restrict__ rowptr, int* __restrict__ wofs) {
    __shared__ int s[1024];
    int tid = threadIdx.x;
    const int C = 10;
    int base = tid * C;
    int loc[C];
    int sum = 0;
    for (int i = 0; i < C; ++i) {
        int idx = base + i;
        int v = (idx < NN) ? cnt[idx] : 0;
        loc[i] = sum;
        sum += v;
    }
    s[tid] = sum;
    __syncthreads();
    for (int off = 1; off < 1024; off <<= 1) {
        int v = (tid >= off) ? s[tid - off] : 0;
        __syncthreads();
        s[tid] += v;
        __syncthreads();
    }
    int prev = (tid == 0) ? 0 : s[tid - 1];
    for (int i = 0; i < C; ++i) {
        int idx = base + i;
        if (idx < NN) {
            int v = prev + loc[i];
            rowptr[idx] = v;
            wofs[idx]   = v;
        }
    }
    if (tid == 1023) rowptr[NN] = s[1023];
}

__global__ void k_scatter(const int* __restrict__ src, const int* __restrict__ dst,
        int* __restrict__ wofs, int* __restrict__ csr) {
    int e = blockIdx.x * blockDim.x + threadIdx.x;
    if (e < NE) {
        int pos = atomicAdd(&wofs[dst[e]], 1);
        csr[pos] = src[e];
    }
}

// ---------------- K3: per-node fused segment-max + MFMA GEMM ----------------
__global__ __launch_bounds__(256, 8) void k_out(const unsigned short* __restrict__ xb,
        const unsigned short* __restrict__ msg, const unsigned short* __restrict__ Wcat,
        const float* __restrict__ bias,
        const int* __restrict__ rowptr, const int* __restrict__ csr,
        float* __restrict__ out) {
    __shared__ __align__(16) unsigned short A[32*136];   // only A now: 8.7 KB
    int tid = threadIdx.x;
    int n = blockIdx.x;

    {   // stage xb rows 0..23; zero rows 24..31 (keeps MFMA inputs NaN-free)
        int c = tid, row = c >> 4, f0 = (c & 15) * 4;
        int b = row / 12, tt = row - b*12;
        *(uint2*)(A + row*136 + f0) =
            *(const uint2*)(xb + ((size_t)(b*NN + n)*12 + tt)*64 + f0);
        if (tid < 128) {
            int c2 = tid + 256, row2 = c2 >> 4, f02 = (c2 & 15)*4;
            int b2 = row2 / 12, tt2 = row2 - b2*12;
            *(uint2*)(A + row2*136 + f02) =
                *(const uint2*)(xb + ((size_t)(b2*NN + n)*12 + tt2)*64 + f02);
        } else {
            unsigned int* z = (unsigned int*)(A + 24*136);
            int i = tid - 128;                 // 128 threads x 5 dwords covers 544
            #pragma unroll
            for (int k = 0; k < 5; ++k) { int j = i + 128*k; if (j < 544) z[j] = 0u; }
        }
    }
    // segment-max gather: per-node msg block is 768 contiguous dwords
    const unsigned int* msg_dw = (const unsigned int*)msg;
    int rp0 = rowptr[n], rp1 = rowptr[n + 1];
    int i0 = tid, i1 = tid + 256, i2 = tid + 512;
    float mlo[3] = {0.f,0.f,0.f}, mhi[3] = {0.f,0.f,0.f};
    int e = rp0;
    for (; e + 4 <= rp1; e += 4) {             // 12 loads in flight
        int s0 = csr[e]*768, s1 = csr[e+1]*768, s2 = csr[e+2]*768, s3 = csr[e+3]*768;
        unsigned int u00 = msg_dw[s0+i0], u01 = msg_dw[s0+i1], u02 = msg_dw[s0+i2];
        unsigned int u10 = msg_dw[s1+i0], u11 = msg_dw[s1+i1], u12 = msg_dw[s1+i2];
        unsigned int u20 = msg_dw[s2+i0], u21 = msg_dw[s2+i1], u22 = msg_dw[s2+i2];
        unsigned int u30 = msg_dw[s3+i0], u31 = msg_dw[s3+i1], u32 = msg_dw[s3+i2];
        mlo[0] = fmaxf(fmaxf(fmaxf(mlo[0], b2f_lo(u00)), fmaxf(b2f_lo(u10), b2f_lo(u20))), b2f_lo(u30));
        mhi[0] = fmaxf(fmaxf(fmaxf(mhi[0], b2f_hi(u00)), fmaxf(b2f_hi(u10), b2f_hi(u20))), b2f_hi(u30));
        mlo[1] = fmaxf(fmaxf(fmaxf(mlo[1], b2f_lo(u01)), fmaxf(b2f_lo(u11), b2f_lo(u21))), b2f_lo(u31));
        mhi[1] = fmaxf(fmaxf(fmaxf(mhi[1], b2f_hi(u01)), fmaxf(b2f_hi(u11), b2f_hi(u21))), b2f_hi(u31));
        mlo[2] = fmaxf(fmaxf(fmaxf(mlo[2], b2f_lo(u02)), fmaxf(b2f_lo(u12), b2f_lo(u22))), b2f_lo(u32));
        mhi[2] = fmaxf(fmaxf(fmaxf(mhi[2], b2f_hi(u02)), fmaxf(b2f_hi(u12), b2f_hi(u22))), b2f_hi(u32));
    }
    for (; e < rp1; ++e) {
        int s0 = csr[e]*768;
        unsigned int u0 = msg_dw[s0+i0], u1 = msg_dw[s0+i1], u2 = msg_dw[s0+i2];
        mlo[0] = fmaxf(mlo[0], b2f_lo(u0));  mhi[0] = fmaxf(mhi[0], b2f_hi(u0));
        mlo[1] = fmaxf(mlo[1], b2f_lo(u1));  mhi[1] = fmaxf(mhi[1], b2f_hi(u1));
        mlo[2] = fmaxf(mlo[2], b2f_lo(u2));  mhi[2] = fmaxf(mhi[2], b2f_hi(u2));
    }
    {   // write neigh cols into A (exact repack: maxes are exact bf16 values)
        unsigned int lo0 = __builtin_bit_cast(unsigned int, mlo[0]) >> 16;
        unsigned int hi0 = __builtin_bit_cast(unsigned int, mhi[0]) & 0xffff0000u;
        *(unsigned int*)(A + (i0>>5)*136 + 64 + (i0&31)*2) = hi0 | lo0;
        unsigned int lo1 = __builtin_bit_cast(unsigned int, mlo[1]) >> 16;
        unsigned int hi1 = __builtin_bit_cast(unsigned int, mhi[1]) & 0xffff0000u;
        *(unsigned int*)(A + (i1>>5)*136 + 64 + (i1&31)*2) = hi1 | lo1;
        unsigned int lo2 = __builtin_bit_cast(unsigned int, mlo[2]) >> 16;
        unsigned int hi2 = __builtin_bit_cast(unsigned int, mhi[2]) & 0xffff0000u;
        *(unsigned int*)(A + (i2>>5)*136 + 64 + (i2&31)*2) = hi2 | lo2;
    }
    __syncthreads();

    int lane = tid & 63, w = tid >> 6;       // wave w owns output cols 16w..16w+15
    int cl = lane & 15, gq = lane >> 4;
    f32x4 acc0 = {}, acc1 = {};
    #pragma unroll
    for (int kk = 0; kk < 4; ++kk) {
        int ko = kk*32 + gq*8;
        bf16x8 b  = *(const bf16x8*)(Wcat + (w*16 + cl)*128 + ko);  // L1-resident
        bf16x8 a0 = *(const bf16x8*)(A + cl*136 + ko);
        bf16x8 a1 = *(const bf16x8*)(A + (16 + cl)*136 + ko);
        acc0 = __builtin_amdgcn_mfma_f32_16x16x32_bf16(a0, b, acc0, 0,0,0);
        acc1 = __builtin_amdgcn_mfma_f32_16x16x32_bf16(a1, b, acc1, 0,0,0);
    }
    float bv = bias[w*16 + cl];
    #pragma unroll
    for (int r = 0; r < 4; ++r) {
        int row = gq*4 + r;
        int b0 = row / 12, tt = row - b0*12;
        out[((size_t)(b0*NN + n)*12 + tt)*64 + w*16 + cl] = acc0[r] + bv;
    }
    if (gq < 2) {
        #pragma unroll
        for (int r = 0; r < 4; ++r) {
            int row = 16 + gq*4 + r;
            int b0 = row / 12, tt = row - b0*12;
            out[((size_t)(b0*NN + n)*12 + tt)*64 + w*16 + cl] = acc1[r] + bv;
        }
    }
}

extern "C" void kernel_launch(void* const* d_in, const int* in_sizes, int n_in,
                              void* d_out, int out_size, void* d_ws, size_t ws_size,
                              hipStream_t stream) {
    const float* x    = (const float*)d_in[0];
    const int*   src  = (const int*)  d_in[1];
    const int*   dst  = (const int*)  d_in[2];
    const float* Wp   = (const float*)d_in[3];
    const float* bp   = (const float*)d_in[4];
    const float* Wn   = (const float*)d_in[5];   // W_neigh
    const float* Wsf  = (const float*)d_in[6];   // W_self
    const float* bias = (const float*)d_in[7];
    float* out = (float*)d_out;

    char* ws = (char*)d_ws;
    int*            cnt    = (int*)           (ws);              // 40000 B
    int*            rowptr = (int*)           (ws + 40064);      // 40004 B
    int*            wofs   = (int*)           (ws + 80128);      // 40000 B
    int*            csr    = (int*)           (ws + 120192);     // 320000 B
    unsigned short* Wp_b   = (unsigned short*)(ws + 440320);     // 8192 B
    unsigned short* Wcat   = (unsigned short*)(ws + 448512);     // 16384 B
    unsigned short* msg    = (unsigned short*)(ws + 464896);     // 30.72 MB
    unsigned short* xb     = (unsigned short*)(ws + 31184896);   // 30.72 MB

    hipMemsetAsync(cnt, 0, NN * sizeof(int), stream);
    k_prep   <<<1, 256, 0, stream>>>(Wp, Wn, Wsf, Wp_b, Wcat);
    k_msg    <<<ROWS/128, 256, 0, stream>>>(x, Wp_b, bp, msg, xb);
    k_count  <<<(NE + 255) / 256, 256, 0, stream>>>(dst, cnt);
    k_scan   <<<1, 1024, 0, stream>>>(cnt, rowptr, wofs);
    k_scatter<<<(NE + 255) / 256, 256, 0, stream>>>(src, dst, wofs, csr);
    k_out    <<<NN, 256, 0, stream>>>(xb, msg, Wcat, bias, rowptr, csr, out);
}